// Round 5
// baseline (567.730 us; speedup 1.0000x reference)
//
#include <hip/hip_runtime.h>
#include <hip/hip_fp16.h>
#include <math.h>

#define NA 50000
#define NB 50000
#define NT (NA + NB)
#define EMB 35
#define EMB2 70
#define EMB3 105
#define DEG 32
#define EH 36      // float offset of mn within an mbuf row
#define MROW 72    // mbuf row: mp[36] + mn[36] floats; 288 B

// ================================================================ transform
struct TArgs {
    const float* fa; const float* fb;
    const float* W[4]; const float* b[4]; const float* att[4];
    __half* emb_main[4];   // [NA][32] halves (64 B rows, elems 0..31)
    __half* emb_tail[4];   // [NA][4]  halves (elems 32,33,34, den=1.0)
    float* sdst[4]; float* ssrc[4];
};

// 128 threads / block, 128 nodes, all 4 cfgs. W + features staged in LDS.
__global__ __launch_bounds__(128) void k_transform(TArgs A) {
    __shared__ float sW[4][35 * 36];   // row-padded to 36 (b128-aligned)
    __shared__ float sAtt[4][70];
    __shared__ float sB[4][35];
    __shared__ float sfa[128 * 37];
    __shared__ float sfb[128 * 37];

    const int t = threadIdx.x;
    const int base = blockIdx.x * 128;

    for (int cfg = 0; cfg < 4; ++cfg) {
        const float* __restrict__ Wg = A.W[cfg];
        for (int i = 0; i < 10; ++i) {
            int idx = i * 128 + t;
            if (idx < 1225) sW[cfg][(idx / 35) * 36 + idx % 35] = Wg[idx];
        }
        if (t < 70) sAtt[cfg][t] = A.att[cfg][t];
        if (t < 35) sB[cfg][t] = A.b[cfg][t];
    }
    for (int i = 0; i < 35; ++i) {
        int idx = i * 128 + t;           // fully sequential over the tile
        int node = base + idx / 35;
        if (node < NA) {
            sfa[(idx / 35) * 37 + idx % 35] = A.fa[(size_t)base * EMB + idx];
            sfb[(idx / 35) * 37 + idx % 35] = A.fb[(size_t)base * EMB + idx];
        }
    }
    __syncthreads();

    const int node = base + t;
    if (node >= NA) return;

    for (int cfg = 0; cfg < 4; ++cfg) {
        const float* __restrict__ srow = (cfg < 2) ? (sfb + t * 37) : (sfa + t * 37);
        const float* __restrict__ arow = (cfg < 2) ? (sfa + t * 37) : (sfb + t * 37);
        const float* __restrict__ Wl = sW[cfg];
        const float* __restrict__ attl = sAtt[cfg];

        float out[EMB];
        #pragma unroll
        for (int j = 0; j < EMB; ++j) out[j] = sB[cfg][j];
        for (int k = 0; k < EMB; ++k) {
            const float xk = srow[k];
            #pragma unroll
            for (int j = 0; j < EMB; ++j) out[j] = fmaf(xk, Wl[k * 36 + j], out[j]);
        }

        float sd = 0.0f, ss = 0.0f;
        #pragma unroll
        for (int j = 0; j < EMB; ++j) sd = fmaf(out[j], attl[EMB + j], sd);
        #pragma unroll
        for (int k = 0; k < EMB; ++k) ss = fmaf(arow[k], attl[k], ss);

        // main: 32 halves = 64 B (one line); tail: 4 halves = 8 B
        float4 f[4];
        __half2* ph = (__half2*)f;
        #pragma unroll
        for (int jj = 0; jj < 16; ++jj)
            ph[jj] = __floats2half2_rn(out[2 * jj], out[2 * jj + 1]);
        float4* md = (float4*)(A.emb_main[cfg] + (size_t)node * 32);
        #pragma unroll
        for (int q = 0; q < 4; ++q) md[q] = f[q];

        float2 tf;
        __half2* tph = (__half2*)&tf;
        tph[0] = __floats2half2_rn(out[32], out[33]);
        tph[1] = __floats2half2_rn(out[34], 1.0f);   // den slot
        *(float2*)(A.emb_tail[cfg] + (size_t)node * 4) = tf;

        A.sdst[cfg][node] = sd;
        A.ssrc[cfg][node] = ss;
    }
}

// ================================================================ aggregate
struct GArgs {
    const int* dst[4];
    const __half* emb_main[4];
    const __half* emb_tail[4];
    const float* sdst[4]; const float* ssrc[4];
    float* mbuf;   // [NT][MROW]
};

// cfg pinned to XCD pair: cfg = (bid&7)>>1 -> each XCD L2 holds ONE 3.6 MB
// table. Wave = 2 nodes (half per node). Lane (e:8, s:4): 4 gather instrs
// cover 32 edges x 64 B, every lane useful, 16 whole lines per instr.
__global__ __launch_bounds__(256) void k_agg(GArgs A) {
    __shared__ unsigned long long pairs[256];   // (w,d) per edge, 2 KB

    const int t = threadIdx.x;
    const int lane = t & 63;
    const int wid = t >> 6;
    const int bid = blockIdx.x;
    const int xcd = bid & 7;
    const int cfg = xcd >> 1;
    const int local = (bid >> 3) * 2 + (xcd & 1);   // 0..6249
    const int pair = local * 4 + wid;               // 0..24999
    const int half = lane >> 5;
    const int l5 = lane & 31;
    const int node = pair * 2 + half;               // 2 nodes per wave

    const int* __restrict__ dst = A.dst[cfg];
    const int d = dst[(size_t)pair * 64 + lane];    // coalesced 256 B
    const float z = A.ssrc[cfg][node] + A.sdst[cfg][d];
    const float tt = (z > 0.0f) ? z : 0.1f * expm1f(z);
    const float w = expf(tt);

    pairs[t] = ((unsigned long long)__float_as_uint(w) << 32) | (unsigned)d;
    __syncthreads();

    const int s4 = l5 & 3;          // slot (16 B) -> 4 consecutive lanes = 1 line
    const int el = l5 >> 2;         // e_local 0..7
    const int pbase = (wid << 6) + (half << 5) + el;
    const __half* __restrict__ em = A.emb_main[cfg];

    float acc[8] = {0, 0, 0, 0, 0, 0, 0, 0};
    #pragma unroll
    for (int g = 0; g < 4; ++g) {
        const unsigned long long pr = pairs[pbase + g * 8];
        const int dg = (int)(unsigned)pr;
        const float wg = __uint_as_float((unsigned)(pr >> 32));
        const float4 v = *(const float4*)(em + ((size_t)dg << 5) + (s4 << 3));
        const __half2* hp = (const __half2*)&v;
        #pragma unroll
        for (int q = 0; q < 4; ++q) {
            const float2 fq = __half22float2(hp[q]);
            acc[2 * q]     = fmaf(wg, fq.x, acc[2 * q]);
            acc[2 * q + 1] = fmaf(wg, fq.y, acc[2 * q + 1]);
        }
    }
    // reduce over e_local (lane bits 2..4)
    #pragma unroll
    for (int m = 4; m <= 16; m <<= 1) {
        #pragma unroll
        for (int j = 0; j < 8; ++j) acc[j] += __shfl_xor(acc[j], m, 64);
    }

    // tail: per-lane edge gather (elems 32..34 + den), butterfly over 32 lanes
    const __half* __restrict__ et = A.emb_tail[cfg];
    const float2 tv = *(const float2*)(et + (size_t)d * 4);
    const __half2* tp = (const __half2*)&tv;
    const float2 t0 = __half22float2(tp[0]);
    const float2 t1 = __half22float2(tp[1]);
    float ta[4] = {w * t0.x, w * t0.y, w * t1.x, w * t1.y};
    #pragma unroll
    for (int m = 1; m <= 16; m <<= 1) {
        #pragma unroll
        for (int j = 0; j < 4; ++j) ta[j] += __shfl_xor(ta[j], m, 64);
    }

    const float rden = 1.0f / ta[3];
    const int side = cfg >> 1;
    const int goff = (cfg & 1) * EH;
    float* __restrict__ mr = A.mbuf + (size_t)(side * NA + node) * MROW + goff;

    if (el == 0) {   // lanes 0..3 / 32..35: elems 8*s4 .. 8*s4+7
        float4 o0, o1;
        o0.x = acc[0] * rden; o0.y = acc[1] * rden;
        o0.z = acc[2] * rden; o0.w = acc[3] * rden;
        o1.x = acc[4] * rden; o1.y = acc[5] * rden;
        o1.z = acc[6] * rden; o1.w = acc[7] * rden;
        *(float4*)(mr + (s4 << 3))     = o0;
        *(float4*)(mr + (s4 << 3) + 4) = o1;
    }
    if (l5 == 4) {   // elems 32..34 (+35 junk)
        float4 ot;
        ot.x = ta[0] * rden; ot.y = ta[1] * rden; ot.z = ta[2] * rden; ot.w = 1.0f;
        *(float4*)(mr + 32) = ot;
    }
}

// ================================================================ MLP
// 256 threads / 256 nodes per block. W1/W2 + feat tile in LDS (78.6 KB ->
// 2 blocks/CU). W reads are same-address broadcasts (no scalar-cache thrash).
// m rows preloaded into 18 float4 regs before staging (latency overlap).
__global__ __launch_bounds__(256) void k_mlp(
        const float* __restrict__ fa, const float* __restrict__ fb,
        const float* __restrict__ mbuf,
        const float* __restrict__ W1, const float* __restrict__ b1,
        const float* __restrict__ alpha_p,
        const float* __restrict__ W2, const float* __restrict__ b2,
        float* __restrict__ out) {
    __shared__ float sW1[105 * 72];   // row-padded
    __shared__ float sW2[70 * 36];
    __shared__ float sB1[70];
    __shared__ float sB2[35];
    __shared__ float sx[256 * 37];

    const int t = threadIdx.x;
    const int base = blockIdx.x * 256;
    const int node = base + t;

    // preload my m row (18 float4, static indices -> registers)
    float4 mv[18];
    if (node < NT) {
        const float4* m4 = (const float4*)(mbuf + (size_t)node * MROW);
        #pragma unroll
        for (int q = 0; q < 18; ++q) mv[q] = m4[q];
    }

    for (int i = 0; i < 29; ++i) {
        int idx = i * 256 + t;
        if (idx < 7350) sW1[(idx / 70) * 72 + idx % 70] = W1[idx];
    }
    for (int i = 0; i < 10; ++i) {
        int idx = i * 256 + t;
        if (idx < 2450) sW2[(idx / 35) * 36 + idx % 35] = W2[idx];
    }
    if (t < 70) sB1[t] = b1[t];
    if (t < 35) sB2[t] = b2[t];
    for (int i = 0; i < 35; ++i) {
        int idx = i * 256 + t;           // sequential over [256][35] tile
        int nn = base + idx / 35;
        if (nn < NT) {
            float v = (nn < NA) ? fa[(size_t)nn * EMB + idx % 35]
                                : fb[(size_t)(nn - NA) * EMB + idx % 35];
            sx[(idx / 35) * 37 + idx % 35] = v;
        }
    }
    __syncthreads();

    if (node >= NT) return;

    float h[EMB2];
    #pragma unroll
    for (int j = 0; j < EMB2; ++j) h[j] = sB1[j];

    for (int k = 0; k < EMB; ++k) {            // feature part
        const float xk = sx[t * 37 + k];
        #pragma unroll
        for (int j = 0; j < EMB2; ++j) h[j] = fmaf(xk, sW1[k * 72 + j], h[j]);
    }
    #pragma unroll
    for (int q = 0; q < 18; ++q) {             // m part (skip den slots 35,71)
        const float c[4] = {mv[q].x, mv[q].y, mv[q].z, mv[q].w};
        #pragma unroll
        for (int ci = 0; ci < 4; ++ci) {
            const int e = q * 4 + ci;
            if (e == 35 || e == 71) continue;
            const int k = (e < 35) ? (35 + e) : (34 + e);
            const float xk = c[ci];
            #pragma unroll
            for (int j = 0; j < EMB2; ++j) h[j] = fmaf(xk, sW1[k * 72 + j], h[j]);
        }
    }

    const float alpha = alpha_p[0];
    float o[EMB];
    #pragma unroll
    for (int m = 0; m < EMB; ++m) o[m] = sB2[m];
    for (int j = 0; j < EMB2; ++j) {
        float hj = h[j];
        hj = (hj > 0.0f) ? hj : alpha * hj;
        #pragma unroll
        for (int m = 0; m < EMB; ++m) o[m] = fmaf(hj, sW2[j * 36 + m], o[m]);
    }

    float* __restrict__ orow = out + (size_t)node * EMB;
    #pragma unroll
    for (int m = 0; m < EMB; ++m) orow[m] = o[m];
}

// ================================================================ launch
extern "C" void kernel_launch(void* const* d_in, const int* in_sizes, int n_in,
                              void* d_out, int out_size, void* d_ws, size_t ws_size,
                              hipStream_t stream) {
    const float* feature_a = (const float*)d_in[0];
    const float* feature_b = (const float*)d_in[1];
    const int* dsts[4] = {(const int*)d_in[2], (const int*)d_in[3],
                          (const int*)d_in[4], (const int*)d_in[5]};
    const float* Wc[4]  = {(const float*)d_in[6],  (const float*)d_in[9],
                           (const float*)d_in[12], (const float*)d_in[15]};
    const float* bc[4]  = {(const float*)d_in[7],  (const float*)d_in[10],
                           (const float*)d_in[13], (const float*)d_in[16]};
    const float* attc[4]= {(const float*)d_in[8],  (const float*)d_in[11],
                           (const float*)d_in[14], (const float*)d_in[17]};
    const float* W1 = (const float*)d_in[18];
    const float* b1 = (const float*)d_in[19];
    const float* alpha = (const float*)d_in[20];
    const float* W2 = (const float*)d_in[21];
    const float* b2 = (const float*)d_in[22];

    char* ws = (char*)d_ws;
    size_t off = 0;
    auto carve = [&](size_t bytes) {
        char* p = ws + off;
        off += (bytes + 255) & ~(size_t)255;
        return p;
    };
    __half* emain[4]; __half* etail[4]; float* sdst[4]; float* ssrc[4];
    for (int c = 0; c < 4; ++c) emain[c] = (__half*)carve((size_t)NA * 32 * 2);
    for (int c = 0; c < 4; ++c) etail[c] = (__half*)carve((size_t)NA * 4 * 2);
    for (int c = 0; c < 4; ++c) sdst[c] = (float*)carve((size_t)NA * 4);
    for (int c = 0; c < 4; ++c) ssrc[c] = (float*)carve((size_t)NA * 4);
    float* mbuf = (float*)carve((size_t)NT * MROW * 4);

    TArgs ta;
    ta.fa = feature_a; ta.fb = feature_b;
    for (int c = 0; c < 4; ++c) {
        ta.W[c] = Wc[c]; ta.b[c] = bc[c]; ta.att[c] = attc[c];
        ta.emb_main[c] = emain[c]; ta.emb_tail[c] = etail[c];
        ta.sdst[c] = sdst[c]; ta.ssrc[c] = ssrc[c];
    }
    k_transform<<<(NA + 127) / 128, 128, 0, stream>>>(ta);

    GArgs ga;
    for (int c = 0; c < 4; ++c) {
        ga.dst[c] = dsts[c]; ga.emb_main[c] = emain[c]; ga.emb_tail[c] = etail[c];
        ga.sdst[c] = sdst[c]; ga.ssrc[c] = ssrc[c];
    }
    ga.mbuf = mbuf;
    k_agg<<<25000, 256, 0, stream>>>(ga);   // cfg = (bid&7)>>1, XCD-pinned

    k_mlp<<<(NT + 255) / 256, 256, 0, stream>>>(feature_a, feature_b, mbuf,
                                                W1, b1, alpha, W2, b2,
                                                (float*)d_out);
}

// Round 6
// 355.708 us; speedup vs baseline: 1.5961x; 1.5961x over previous
//
#include <hip/hip_runtime.h>
#include <hip/hip_fp16.h>
#include <math.h>

#define NA 50000
#define NB 50000
#define NT (NA + NB)
#define EMB 35
#define EMB2 70
#define EMB3 105
#define DEG 32
#define EH 36      // float offset of mn within an mbuf row
#define MROW 72    // mbuf row: mp[36] + mn[36] floats; 288 B

// ================================================================ transform
struct TArgs {
    const float* fa; const float* fb;
    const float* W[4]; const float* b[4]; const float* att[4];
    __half* emb_main[4];   // [NA][32] halves (64 B rows, elems 0..31)
    __half* emb_tail[4];   // [NA][4]  halves (elems 32,33,34, den=1.0)
    float* sdst[4]; float* ssrc[4];
};

// blockIdx.y = cfg (4x wave count). W/att/b in LDS (5.3 KB, broadcast reads);
// feature rows streamed from global (consecutive threads -> L1-resident lines).
__global__ __launch_bounds__(256) void k_transform(TArgs A) {
    __shared__ float sW[35 * 35];
    __shared__ float sAtt[70];
    __shared__ float sB[35];

    const int t = threadIdx.x;
    const int cfg = blockIdx.y;

    const float* __restrict__ Wg = A.W[cfg];
    for (int i = t; i < 1225; i += 256) sW[i] = Wg[i];
    if (t < 70) sAtt[t] = A.att[cfg][t];
    if (t < 35) sB[t] = A.b[cfg][t];
    __syncthreads();

    const int node = blockIdx.x * 256 + t;
    if (node >= NA) return;

    const float* __restrict__ srcf = (cfg < 2) ? A.fb : A.fa;  // transformed
    const float* __restrict__ attf = (cfg < 2) ? A.fa : A.fb;  // scores s_src
    const float* __restrict__ srow = srcf + (size_t)node * EMB;
    const float* __restrict__ arow = attf + (size_t)node * EMB;

    float out[EMB];
    #pragma unroll
    for (int j = 0; j < EMB; ++j) out[j] = sB[j];

    for (int k = 0; k < EMB; ++k) {
        const float xk = srow[k];
        #pragma unroll
        for (int j = 0; j < EMB; ++j) out[j] = fmaf(xk, sW[k * 35 + j], out[j]);
    }

    float sd = 0.0f, ss = 0.0f;
    #pragma unroll
    for (int j = 0; j < EMB; ++j) sd = fmaf(out[j], sAtt[EMB + j], sd);
    for (int k = 0; k < EMB; ++k) ss = fmaf(arow[k], sAtt[k], ss);

    // main: 32 halves = 64 B (one line); tail: 4 halves = 8 B
    float4 f[4];
    __half2* ph = (__half2*)f;
    #pragma unroll
    for (int jj = 0; jj < 16; ++jj)
        ph[jj] = __floats2half2_rn(out[2 * jj], out[2 * jj + 1]);
    float4* md = (float4*)(A.emb_main[cfg] + (size_t)node * 32);
    #pragma unroll
    for (int q = 0; q < 4; ++q) md[q] = f[q];

    float2 tf;
    __half2* tph = (__half2*)&tf;
    tph[0] = __floats2half2_rn(out[32], out[33]);
    tph[1] = __floats2half2_rn(out[34], 1.0f);   // den slot
    *(float2*)(A.emb_tail[cfg] + (size_t)node * 4) = tf;

    A.sdst[cfg][node] = sd;
    A.ssrc[cfg][node] = ss;
}

// ================================================================ aggregate
struct GArgs {
    const int* dst[4];
    const __half* emb_main[4];
    const __half* emb_tail[4];
    const float* sdst[4]; const float* ssrc[4];
    float* mbuf;   // [NT][MROW]
};

// cfg pinned to XCD pair: cfg = (bid&7)>>1 -> each XCD L2 holds ONE 3.6 MB
// table. Wave = 2 nodes (half per node). Lane (e:8, s:4): 4 gather instrs
// cover 32 edges x 64 B, every lane useful, 16 whole lines per instr.
__global__ __launch_bounds__(256) void k_agg(GArgs A) {
    __shared__ unsigned long long pairs[256];   // (w,d) per edge, 2 KB

    const int t = threadIdx.x;
    const int lane = t & 63;
    const int wid = t >> 6;
    const int bid = blockIdx.x;
    const int xcd = bid & 7;
    const int cfg = xcd >> 1;
    const int local = (bid >> 3) * 2 + (xcd & 1);   // 0..6249
    const int pair = local * 4 + wid;               // 0..24999
    const int half = lane >> 5;
    const int l5 = lane & 31;
    const int node = pair * 2 + half;               // 2 nodes per wave

    const int* __restrict__ dst = A.dst[cfg];
    const int d = dst[(size_t)pair * 64 + lane];    // coalesced 256 B
    const float z = A.ssrc[cfg][node] + A.sdst[cfg][d];
    const float tt = (z > 0.0f) ? z : 0.1f * expm1f(z);
    const float w = expf(tt);

    pairs[t] = ((unsigned long long)__float_as_uint(w) << 32) | (unsigned)d;
    __syncthreads();

    const int s4 = l5 & 3;          // slot (16 B) -> 4 consecutive lanes = 1 line
    const int el = l5 >> 2;         // e_local 0..7
    const int pbase = (wid << 6) + (half << 5) + el;
    const __half* __restrict__ em = A.emb_main[cfg];

    float acc[8] = {0, 0, 0, 0, 0, 0, 0, 0};
    #pragma unroll
    for (int g = 0; g < 4; ++g) {
        const unsigned long long pr = pairs[pbase + g * 8];
        const int dg = (int)(unsigned)pr;
        const float wg = __uint_as_float((unsigned)(pr >> 32));
        const float4 v = *(const float4*)(em + ((size_t)dg << 5) + (s4 << 3));
        const __half2* hp = (const __half2*)&v;
        #pragma unroll
        for (int q = 0; q < 4; ++q) {
            const float2 fq = __half22float2(hp[q]);
            acc[2 * q]     = fmaf(wg, fq.x, acc[2 * q]);
            acc[2 * q + 1] = fmaf(wg, fq.y, acc[2 * q + 1]);
        }
    }
    // reduce over e_local (lane bits 2..4)
    #pragma unroll
    for (int m = 4; m <= 16; m <<= 1) {
        #pragma unroll
        for (int j = 0; j < 8; ++j) acc[j] += __shfl_xor(acc[j], m, 64);
    }

    // tail: per-lane edge gather (elems 32..34 + den), butterfly over 32 lanes
    const __half* __restrict__ et = A.emb_tail[cfg];
    const float2 tv = *(const float2*)(et + (size_t)d * 4);
    const __half2* tp = (const __half2*)&tv;
    const float2 t0 = __half22float2(tp[0]);
    const float2 t1 = __half22float2(tp[1]);
    float ta[4] = {w * t0.x, w * t0.y, w * t1.x, w * t1.y};
    #pragma unroll
    for (int m = 1; m <= 16; m <<= 1) {
        #pragma unroll
        for (int j = 0; j < 4; ++j) ta[j] += __shfl_xor(ta[j], m, 64);
    }

    const float rden = 1.0f / ta[3];
    const int side = cfg >> 1;
    const int goff = (cfg & 1) * EH;
    float* __restrict__ mr = A.mbuf + (size_t)(side * NA + node) * MROW + goff;

    if (el == 0) {   // lanes 0..3 / 32..35: elems 8*s4 .. 8*s4+7
        float4 o0, o1;
        o0.x = acc[0] * rden; o0.y = acc[1] * rden;
        o0.z = acc[2] * rden; o0.w = acc[3] * rden;
        o1.x = acc[4] * rden; o1.y = acc[5] * rden;
        o1.z = acc[6] * rden; o1.w = acc[7] * rden;
        *(float4*)(mr + (s4 << 3))     = o0;
        *(float4*)(mr + (s4 << 3) + 4) = o1;
    }
    if (l5 == 4) {   // elems 32..34 (+35 junk=1.0)
        float4 ot;
        ot.x = ta[0] * rden; ot.y = ta[1] * rden; ot.z = ta[2] * rden; ot.w = 1.0f;
        *(float4*)(mr + 32) = ot;
    }
}

// ================================================================ MLP
// Weights-ONLY LDS (39.6 KB -> 4 blocks/CU); broadcast ds_reads. x streamed
// from global per-thread (L1-resident lines), m float4s consumed inline (no
// preload array -> no spills). h[70]/o[35] statically indexed everywhere.
__global__ __launch_bounds__(256) void k_mlp(
        const float* __restrict__ fa, const float* __restrict__ fb,
        const float* __restrict__ mbuf,
        const float* __restrict__ W1, const float* __restrict__ b1,
        const float* __restrict__ alpha_p,
        const float* __restrict__ W2, const float* __restrict__ b2,
        float* __restrict__ out) {
    __shared__ float sW1[105 * 70];   // 29400 B
    __shared__ float sW2[70 * 35];    // 9800 B
    __shared__ float sB1[70];
    __shared__ float sB2[35];

    const int t = threadIdx.x;
    for (int i = t; i < 7350; i += 256) sW1[i] = W1[i];
    for (int i = t; i < 2450; i += 256) sW2[i] = W2[i];
    if (t < 70) sB1[t] = b1[t];
    if (t < 35) sB2[t] = b2[t];
    __syncthreads();

    const int node = blockIdx.x * 256 + t;
    if (node >= NT) return;

    const float* __restrict__ frow =
        (node < NA) ? (fa + (size_t)node * EMB) : (fb + (size_t)(node - NA) * EMB);
    const float* __restrict__ mrow = mbuf + (size_t)node * MROW;

    float h[EMB2];
    #pragma unroll
    for (int j = 0; j < EMB2; ++j) h[j] = sB1[j];

    for (int k = 0; k < EMB; ++k) {            // feature part (k = 0..34)
        const float xk = frow[k];
        #pragma unroll
        for (int j = 0; j < EMB2; ++j) h[j] = fmaf(xk, sW1[k * EMB2 + j], h[j]);
    }
    for (int q = 0; q < 18; ++q) {             // m part, float4 consumed inline
        const float4 v = ((const float4*)mrow)[q];
        const float c[4] = {v.x, v.y, v.z, v.w};
        #pragma unroll
        for (int ci = 0; ci < 4; ++ci) {
            const int e = q * 4 + ci;          // mbuf elem index
            if (e == 35 || e == 71) continue;  // den slots (uniform skip)
            const int k = (e < 35) ? (35 + e) : (34 + e);
            const float xk = c[ci];
            #pragma unroll
            for (int j = 0; j < EMB2; ++j) h[j] = fmaf(xk, sW1[k * EMB2 + j], h[j]);
        }
    }

    const float alpha = alpha_p[0];
    float o[EMB];
    #pragma unroll
    for (int m = 0; m < EMB; ++m) o[m] = sB2[m];
    #pragma unroll                             // j static -> h[j] stays in regs
    for (int j = 0; j < EMB2; ++j) {
        float hj = h[j];
        hj = (hj > 0.0f) ? hj : alpha * hj;
        #pragma unroll
        for (int m = 0; m < EMB; ++m) o[m] = fmaf(hj, sW2[j * 35 + m], o[m]);
    }

    float* __restrict__ orow = out + (size_t)node * EMB;
    #pragma unroll
    for (int m = 0; m < EMB; ++m) orow[m] = o[m];
}

// ================================================================ launch
extern "C" void kernel_launch(void* const* d_in, const int* in_sizes, int n_in,
                              void* d_out, int out_size, void* d_ws, size_t ws_size,
                              hipStream_t stream) {
    const float* feature_a = (const float*)d_in[0];
    const float* feature_b = (const float*)d_in[1];
    const int* dsts[4] = {(const int*)d_in[2], (const int*)d_in[3],
                          (const int*)d_in[4], (const int*)d_in[5]};
    const float* Wc[4]  = {(const float*)d_in[6],  (const float*)d_in[9],
                           (const float*)d_in[12], (const float*)d_in[15]};
    const float* bc[4]  = {(const float*)d_in[7],  (const float*)d_in[10],
                           (const float*)d_in[13], (const float*)d_in[16]};
    const float* attc[4]= {(const float*)d_in[8],  (const float*)d_in[11],
                           (const float*)d_in[14], (const float*)d_in[17]};
    const float* W1 = (const float*)d_in[18];
    const float* b1 = (const float*)d_in[19];
    const float* alpha = (const float*)d_in[20];
    const float* W2 = (const float*)d_in[21];
    const float* b2 = (const float*)d_in[22];

    char* ws = (char*)d_ws;
    size_t off = 0;
    auto carve = [&](size_t bytes) {
        char* p = ws + off;
        off += (bytes + 255) & ~(size_t)255;
        return p;
    };
    __half* emain[4]; __half* etail[4]; float* sdst[4]; float* ssrc[4];
    for (int c = 0; c < 4; ++c) emain[c] = (__half*)carve((size_t)NA * 32 * 2);
    for (int c = 0; c < 4; ++c) etail[c] = (__half*)carve((size_t)NA * 4 * 2);
    for (int c = 0; c < 4; ++c) sdst[c] = (float*)carve((size_t)NA * 4);
    for (int c = 0; c < 4; ++c) ssrc[c] = (float*)carve((size_t)NA * 4);
    float* mbuf = (float*)carve((size_t)NT * MROW * 4);

    TArgs ta;
    ta.fa = feature_a; ta.fb = feature_b;
    for (int c = 0; c < 4; ++c) {
        ta.W[c] = Wc[c]; ta.b[c] = bc[c]; ta.att[c] = attc[c];
        ta.emb_main[c] = emain[c]; ta.emb_tail[c] = etail[c];
        ta.sdst[c] = sdst[c]; ta.ssrc[c] = ssrc[c];
    }
    dim3 g1((NA + 255) / 256, 4);
    k_transform<<<g1, 256, 0, stream>>>(ta);

    GArgs ga;
    for (int c = 0; c < 4; ++c) {
        ga.dst[c] = dsts[c]; ga.emb_main[c] = emain[c]; ga.emb_tail[c] = etail[c];
        ga.sdst[c] = sdst[c]; ga.ssrc[c] = ssrc[c];
    }
    ga.mbuf = mbuf;
    k_agg<<<25000, 256, 0, stream>>>(ga);   // cfg = (bid&7)>>1, XCD-pinned

    k_mlp<<<(NT + 255) / 256, 256, 0, stream>>>(feature_a, feature_b, mbuf,
                                                W1, b1, alpha, W2, b2,
                                                (float*)d_out);
}